// Round 2
// baseline (14049.985 us; speedup 1.0000x reference)
//
#include <hip/hip_runtime.h>

#define TT 1024
#define BB 64
#define IN_ 512
#define HID_ 512
#define KTOT 1024
#define SLICE (BB * HID_)  // 32768 floats, one [t] slice of out / one Xt slice

#define AGENT __HIP_MEMORY_SCOPE_AGENT

typedef float v2f __attribute__((ext_vector_type(2)));

__device__ __forceinline__ float sigmoid_fast(float x) {
  return 1.0f / (1.0f + __expf(-x));
}

__device__ __forceinline__ float tanh_fast(float x) {
  float ax = fabsf(x);
  float e = __expf(2.0f * ax);          // >= 1, inf-safe
  float r = 1.0f - 2.0f / (e + 1.0f);   // in [0,1)
  return copysignf(r, x);
}

// LLC-coherent (device-scope, relaxed) load/store: emits global_load/store
// with sc0 sc1 — bypasses the non-coherent per-XCD L2, NO cache flush needed.
__device__ __forceinline__ float ld_llc(const float* p) {
  return __hip_atomic_load(const_cast<float*>(p), __ATOMIC_RELAXED, AGENT);
}
__device__ __forceinline__ unsigned long long ld_llc64(const unsigned long long* p) {
  return __hip_atomic_load(const_cast<unsigned long long*>(p), __ATOMIC_RELAXED, AGENT);
}
__device__ __forceinline__ void st_llc(float* p, float v) {
  __hip_atomic_store(p, v, __ATOMIC_RELAXED, AGENT);
}

// Hand-rolled grid barrier: monotonic counter, relaxed agent atomics (no L2
// writeback/invalidate). The __syncthreads() before the arrive drains vmcnt(0),
// so all of this block's sc H-stores have reached the LLC before the add lands.
__device__ __forceinline__ void gridbar(unsigned* ctr, unsigned target) {
  __syncthreads();
  if (threadIdx.x == 0) {
    __hip_atomic_fetch_add(ctr, 1u, __ATOMIC_RELAXED, AGENT);
    while (__hip_atomic_load(ctr, __ATOMIC_RELAXED, AGENT) < target)
      __builtin_amdgcn_s_sleep(2);
  }
  __syncthreads();
}

// Reduce-scatter swap helpers (gfx950 permlane swaps, VALU-rate, no DS pipe).
// After swap+add on (a=vals[r], b=vals[r+half]):
//   low lane-group holds vals[r] pair-summed, high group holds vals[r+half].
__device__ __forceinline__ float plswap32_sum(float a, float b) {
  asm("v_permlane32_swap_b32 %0, %1" : "+v"(a), "+v"(b));
  return a + b;
}
__device__ __forceinline__ float plswap16_sum(float a, float b) {
  asm("v_permlane16_swap_b32 %0, %1" : "+v"(a), "+v"(b));
  return a + b;
}

// Build masked, transposed, gate-interleaved weights: W4[k][j][g]
__global__ void prep_weights(const float* __restrict__ Wx,
                             const float* __restrict__ Wh,
                             const float* __restrict__ thr,
                             float* __restrict__ W4, unsigned* __restrict__ ctr) {
  if (blockIdx.x == 0 && threadIdx.x == 0) *ctr = 0;  // barrier init (ws is poisoned)
  int idx = blockIdx.x * 256 + threadIdx.x;  // = k*512 + j
  int k = idx >> 9;
  int j = idx & 511;
  float4 w4;
  float* wp = reinterpret_cast<float*>(&w4);
#pragma unroll
  for (int g = 0; g < 4; ++g) {
    float w, th;
    if (k < IN_) {
      w = Wx[(g * HID_ + j) * IN_ + k];
      th = thr[j * 8 + g];
    } else {
      w = Wh[(g * HID_ + j) * HID_ + (k - IN_)];
      th = thr[j * 8 + 4 + g];
    }
    float m = ((fabsf(w) - th) >= 0.0f) ? 1.0f : 0.0f;  // unit_step(|w|-thr)
    wp[g] = w * m;
  }
  reinterpret_cast<float4*>(W4)[idx] = w4;
}

// Transpose X[t][b][k] -> Xt[t][k][b], stored in out slice (t+1); last to xlast.
__global__ void transpose_x(const float* __restrict__ X,
                            float* __restrict__ out,
                            float* __restrict__ xlast) {
  __shared__ float tile[64][129];
  int t = blockIdx.x >> 2;
  int k0 = (blockIdx.x & 3) * 128;
  const float* src = X + (size_t)t * (BB * IN_) + k0;
#pragma unroll
  for (int j = 0; j < 8; ++j) {
    int f = threadIdx.x + j * 256;   // float4 index in 64x128 tile
    int b = f >> 5;
    int m = (f & 31) * 4;
    float4 v = *reinterpret_cast<const float4*>(src + b * IN_ + m);
    tile[b][m + 0] = v.x; tile[b][m + 1] = v.y;
    tile[b][m + 2] = v.z; tile[b][m + 3] = v.w;
  }
  __syncthreads();
  float* dst = (t < TT - 1) ? (out + (size_t)(t + 1) * SLICE) : xlast;
  int b = threadIdx.x & 63;
  int ks = threadIdx.x >> 6;
#pragma unroll
  for (int u = 0; u < 32; ++u) {
    int kk = ks * 32 + u;
    dst[(k0 + kk) * BB + b] = tile[b][kk];
  }
}

// Persistent LSTM: 256 blocks x 512 threads, 1 block/CU.
// Thread mapping: tid = ks*8 + bt, ks in [0,64) = 16-k slice, bt in [0,8) = 8-b tile.
// Each LDS weight float4 feeds 8 batch elements' FMAs (register blocking)
// -> LDS b128 traffic per CU per step is 256 reads (was 2048 pre-round-0).
// Activations straight from global: X via L2-cached float4, Hprev via 64-bit
// LLC-coherent loads. Cross-k-slice reduction: within-wave permlane swap
// butterfly (3 stages) + 18 KB LDS cross-wave combine.
// Weight swizzle: f4' = (k*2+r) ^ (((k>>4)&3)<<1 | ((k>>6)&1)).
//   Bijective: XOR source bits (k4..k6) are disjoint from target bits (0..2).
//   Conflict-free: per instruction the wave's 8 unique addresses take all 8
//   low-3-bit values (swz is a bijection of ks mod 8).
__global__ void __launch_bounds__(512, 2) lstm_rec(
    const float* __restrict__ W4, const float* __restrict__ bias,
    const float* __restrict__ h0p, const float* __restrict__ c0p,
    float* __restrict__ Hb0, float* __restrict__ Hb1,
    const float* __restrict__ xlast, float* __restrict__ out,
    unsigned* __restrict__ ctr) {
  __shared__ float wlds[KTOT * 8];      // 32 KB, XOR-swizzled float4 slots
  __shared__ float red3[8 * 8 * 72];    // [wave][hg][bt*9 + i], 18 KB, 9-pad
  const int tid = threadIdx.x;
  const int blk = blockIdx.x;
  const int wv = __builtin_amdgcn_readfirstlane(tid >> 6);  // wave id 0..7
  const int lane = tid & 63;
  const int ks = tid >> 3;   // k-slice 0..63 (16 k each); waves 0-3 = X, 4-7 = H
  const int bt = tid & 7;    // b-tile (8 consecutive batch elems)
  const int h0c = blk * 2;
  unsigned bar_target = 256;

  // One-time weight stage into LDS (XOR-swizzled, bijective).
  {
    const float4* Wsrc = reinterpret_cast<const float4*>(W4);
    float4* Wdst = reinterpret_cast<float4*>(wlds);
    for (int i = tid; i < KTOT * 2; i += 512) {
      int k = i >> 1, r = i & 1;
      int swz = (((k >> 4) & 3) << 1) | ((k >> 6) & 1);
      Wdst[((k * 2) + r) ^ swz] = Wsrc[(k << 9) + h0c + r];
    }
  }

  // Init: H_{-1} = h0 into Hb0 in [h][b] layout (LLC-coherent); C from c0.
  float C = 0.0f;
  float bias_r[4] = {0.f, 0.f, 0.f, 0.f};
  if (tid < 128) {
    int hh = h0c + (tid >> 6);
    int b = tid & 63;
    st_llc(&Hb0[hh * BB + b], h0p[b * HID_ + hh]);
    C = c0p[b * HID_ + hh];
#pragma unroll
    for (int g = 0; g < 4; ++g) bias_r[g] = bias[g * HID_ + hh];
  }
  gridbar(ctr, bar_target); bar_target += 256;

  // Thread-invariant swizzled W base (ks*32 is 32-aligned; swz<8 stays in-tile).
  const int swz = ((ks & 3) << 1) | ((ks >> 2) & 1);
  const float4* wbase = reinterpret_cast<const float4*>(wlds) + ks * 32;

  for (int t = 0; t < TT; ++t) {
    const float* Hprev = (t & 1) ? Hb1 : Hb0;
    float* Hnext = (t & 1) ? Hb0 : Hb1;
    const float* Xs = (t < TT - 1) ? (out + (size_t)(t + 1) * SLICE) : xlast;

    // acc[h][g][bpair] : 32 v2f = 64 floats, fully static-indexed.
    v2f acc[2][4][4];
#pragma unroll
    for (int h = 0; h < 2; ++h)
#pragma unroll
      for (int g = 0; g < 4; ++g)
#pragma unroll
        for (int p = 0; p < 4; ++p) acc[h][g][p] = (v2f){0.f, 0.f};

    if (wv < 4) {
      // X half: k = ks*16 + j, normal L2-cached loads, 8 b per thread.
      const float4* Ax = reinterpret_cast<const float4*>(Xs) + ks * 256 + bt * 2;
#pragma unroll 4
      for (int j = 0; j < 16; ++j) {
        float4 a0 = Ax[j * 16];
        float4 a1 = Ax[j * 16 + 1];
        float4 wa = wbase[(j * 2) ^ swz];
        float4 wb = wbase[(j * 2 + 1) ^ swz];
        v2f av[4] = {{a0.x, a0.y}, {a0.z, a0.w}, {a1.x, a1.y}, {a1.z, a1.w}};
        const float wg[2][4] = {{wa.x, wa.y, wa.z, wa.w},
                                {wb.x, wb.y, wb.z, wb.w}};
#pragma unroll
        for (int h = 0; h < 2; ++h)
#pragma unroll
          for (int g = 0; g < 4; ++g) {
            v2f wvv = {wg[h][g], wg[h][g]};
#pragma unroll
            for (int p = 0; p < 4; ++p)
              acc[h][g][p] = __builtin_elementwise_fma(wvv, av[p], acc[h][g][p]);
          }
      }
    } else {
      // H half: LLC-coherent 64-bit loads (global_load_dwordx2 sc0 sc1).
      const unsigned long long* Ah =
          reinterpret_cast<const unsigned long long*>(Hprev) +
          (ks * 16 - IN_) * 32 + bt * 4;
#pragma unroll 4
      for (int j = 0; j < 16; ++j) {
        unsigned long long q0 = ld_llc64(Ah + j * 32 + 0);
        unsigned long long q1 = ld_llc64(Ah + j * 32 + 1);
        unsigned long long q2 = ld_llc64(Ah + j * 32 + 2);
        unsigned long long q3 = ld_llc64(Ah + j * 32 + 3);
        float4 wa = wbase[(j * 2) ^ swz];
        float4 wb = wbase[(j * 2 + 1) ^ swz];
        v2f av[4] = {__builtin_bit_cast(v2f, q0), __builtin_bit_cast(v2f, q1),
                     __builtin_bit_cast(v2f, q2), __builtin_bit_cast(v2f, q3)};
        const float wg[2][4] = {{wa.x, wa.y, wa.z, wa.w},
                                {wb.x, wb.y, wb.z, wb.w}};
#pragma unroll
        for (int h = 0; h < 2; ++h)
#pragma unroll
          for (int g = 0; g < 4; ++g) {
            v2f wvv = {wg[h][g], wg[h][g]};
#pragma unroll
            for (int p = 0; p < 4; ++p)
              acc[h][g][p] = __builtin_elementwise_fma(wvv, av[p], acc[h][g][p]);
          }
      }
    }

    // ---- Reduce over the 8 k-slices inside this wave (lane bits 3..5). ----
    // vals idx = hg*8 + i, hg = h*4+g, i = b-within-tile. After 3 stages the
    // lane with (lane>>3)&7 == hg holds vals[i] = sum over its wave's 8 ks.
    float vals[64];
#pragma unroll
    for (int h = 0; h < 2; ++h)
#pragma unroll
      for (int g = 0; g < 4; ++g)
#pragma unroll
        for (int p = 0; p < 4; ++p) {
          vals[(h * 4 + g) * 8 + p * 2]     = acc[h][g][p].x;
          vals[(h * 4 + g) * 8 + p * 2 + 1] = acc[h][g][p].y;
        }
#pragma unroll
    for (int r = 0; r < 32; ++r) vals[r] = plswap32_sum(vals[r], vals[r + 32]);
#pragma unroll
    for (int r = 0; r < 16; ++r) vals[r] = plswap16_sum(vals[r], vals[r + 16]);
    {
      const bool hi = (lane & 8) != 0;
#pragma unroll
      for (int r = 0; r < 8; ++r) {
        float keep = hi ? vals[r + 8] : vals[r];
        float send = hi ? vals[r] : vals[r + 8];
        vals[r] = keep + __shfl_xor(send, 8, 64);
      }
    }
    // Cross-wave combine via LDS: 32 B per thread.
    {
      int hgo = (lane >> 3) & 7;
      float* rp = &red3[(wv * 8 + hgo) * 72 + bt * 9];
#pragma unroll
      for (int i = 0; i < 8; ++i) rp[i] = vals[i];
    }
    __syncthreads();

    if (tid < 128) {
      int hsub = tid >> 6;
      int hh = h0c + hsub;
      int b = tid & 63;
      int boff = (b >> 3) * 9 + (b & 7);
      float gs[4];
#pragma unroll
      for (int g = 0; g < 4; ++g) {
        float s = bias_r[g];
#pragma unroll
        for (int w = 0; w < 8; ++w) s += red3[(w * 8 + hsub * 4 + g) * 72 + boff];
        gs[g] = s;
      }
      float I = sigmoid_fast(gs[0]);
      float F = sigmoid_fast(gs[1]);
      float O = sigmoid_fast(gs[2]);
      float Ctl = tanh_fast(gs[3]);
      C = F * C + I * Ctl;
      float H = O * tanh_fast(C);
      out[(size_t)t * SLICE + b * HID_ + hh] = H;  // final output (normal store)
      st_llc(&Hnext[hh * BB + b], H);              // coherent H for next step
    }
    gridbar(ctr, bar_target); bar_target += 256;  // also guards red3 reuse
  }
}

extern "C" void kernel_launch(void* const* d_in, const int* in_sizes, int n_in,
                              void* d_out, int out_size, void* d_ws, size_t ws_size,
                              hipStream_t stream) {
  (void)in_sizes; (void)n_in; (void)out_size; (void)ws_size;
  const float* X    = (const float*)d_in[0];
  const float* Wx   = (const float*)d_in[1];
  const float* Wh   = (const float*)d_in[2];
  const float* bias = (const float*)d_in[3];
  const float* thr  = (const float*)d_in[4];
  const float* h0p  = (const float*)d_in[5];
  const float* c0p  = (const float*)d_in[6];
  float* out = (float*)d_out;

  // ws layout (floats): W4 [1024][512][4] | Hb0 | Hb1 | xlast | ctr (~8.8 MB)
  float* W4 = (float*)d_ws;
  float* Hb0 = W4 + (size_t)KTOT * HID_ * 4;
  float* Hb1 = Hb0 + SLICE;
  float* xlast = Hb1 + SLICE;
  unsigned* ctr = (unsigned*)(xlast + SLICE);

  prep_weights<<<(KTOT * HID_) / 256, 256, 0, stream>>>(Wx, Wh, thr, W4, ctr);
  transpose_x<<<TT * 4, 256, 0, stream>>>(X, out, xlast);

  void* args[] = {&W4, &bias, &h0p, &c0p, &Hb0, &Hb1, &xlast, &out, &ctr};
  hipLaunchCooperativeKernel(reinterpret_cast<void*>(lstm_rec),
                             dim3(256), dim3(512), args, 0, stream);
}

// Round 5
// 12974.103 us; speedup vs baseline: 1.0829x; 1.0829x over previous
//
#include <hip/hip_runtime.h>

#define TT 1024
#define BB 64
#define IN_ 512
#define HID_ 512
#define KTOT 1024
#define SLICE (BB * HID_)  // 32768 floats, one [t] slice of out / one Xt slice

#define AGENT __HIP_MEMORY_SCOPE_AGENT

typedef float v2f __attribute__((ext_vector_type(2)));
typedef float v4f __attribute__((ext_vector_type(4)));

__device__ __forceinline__ float sigmoid_fast(float x) {
  return 1.0f / (1.0f + __expf(-x));
}

__device__ __forceinline__ float tanh_fast(float x) {
  float ax = fabsf(x);
  float e = __expf(2.0f * ax);          // >= 1, inf-safe
  float r = 1.0f - 2.0f / (e + 1.0f);   // in [0,1)
  return copysignf(r, x);
}

// LLC-coherent store WITH COMPLETION ACK: atomic exchange returns the old
// value, so vmcnt clears only when the op has completed AT the LLC (a plain
// sc0 sc1 store may ack before LLC insertion — suspected cause of the
// round-3/4 stale-read failures when readers issue bursts right after the
// barrier). The returned value is kept alive via asm sink so the compiler
// emits the returning form.
__device__ __forceinline__ void st_llc_ack(float* p, float v) {
  float old = __hip_atomic_exchange(p, v, __ATOMIC_RELAXED, AGENT);
  asm volatile("" :: "v"(old));
}

// LLC-coherent 16B load, issued WITHOUT waitcnt — caller must s_waitcnt
// before reading the result (counted-vmcnt pipeline, T3/T4 pattern).
// asm volatile + "memory": cannot be hoisted across the grid barrier.
__device__ __forceinline__ v4f ld_llc128_async(const v4f* p) {
  v4f r;
  asm volatile("global_load_dwordx4 %0, %1, off sc0 sc1"
               : "=&v"(r) : "v"(p) : "memory");
  return r;
}

// Hand-rolled grid barrier: monotonic counter, relaxed agent atomics (no L2
// writeback/invalidate). The __syncthreads() before the arrive drains
// vmcnt(0); with st_llc_ack stores that drain now means "complete at LLC".
// Trailing compiler fence: no memory op may be scheduled above the barrier.
__device__ __forceinline__ void gridbar(unsigned* ctr, unsigned target) {
  __syncthreads();
  if (threadIdx.x == 0) {
    __hip_atomic_fetch_add(ctr, 1u, __ATOMIC_RELAXED, AGENT);
    while (__hip_atomic_load(ctr, __ATOMIC_RELAXED, AGENT) < target)
      __builtin_amdgcn_s_sleep(2);
  }
  __syncthreads();
  asm volatile("" ::: "memory");
}

// Reduce-scatter swap helpers (gfx950 permlane swaps, VALU-rate, no DS pipe).
// After swap+add on (a=vals[r], b=vals[r+half]):
//   low lane-group holds vals[r] pair-summed, high group holds vals[r+half].
__device__ __forceinline__ float plswap32_sum(float a, float b) {
  asm("v_permlane32_swap_b32 %0, %1" : "+v"(a), "+v"(b));
  return a + b;
}
__device__ __forceinline__ float plswap16_sum(float a, float b) {
  asm("v_permlane16_swap_b32 %0, %1" : "+v"(a), "+v"(b));
  return a + b;
}

// Build masked, transposed, gate-interleaved weights: W4[k][j][g]
__global__ void prep_weights(const float* __restrict__ Wx,
                             const float* __restrict__ Wh,
                             const float* __restrict__ thr,
                             float* __restrict__ W4, unsigned* __restrict__ ctr) {
  if (blockIdx.x == 0 && threadIdx.x == 0) *ctr = 0;  // barrier init (ws is poisoned)
  int idx = blockIdx.x * 256 + threadIdx.x;  // = k*512 + j
  int k = idx >> 9;
  int j = idx & 511;
  float4 w4;
  float* wp = reinterpret_cast<float*>(&w4);
#pragma unroll
  for (int g = 0; g < 4; ++g) {
    float w, th;
    if (k < IN_) {
      w = Wx[(g * HID_ + j) * IN_ + k];
      th = thr[j * 8 + g];
    } else {
      w = Wh[(g * HID_ + j) * HID_ + (k - IN_)];
      th = thr[j * 8 + 4 + g];
    }
    float m = ((fabsf(w) - th) >= 0.0f) ? 1.0f : 0.0f;  // unit_step(|w|-thr)
    wp[g] = w * m;
  }
  reinterpret_cast<float4*>(W4)[idx] = w4;
}

// Transpose X[t][b][k] -> Xt[t][k][b], stored in out slice (t+1); last to xlast.
__global__ void transpose_x(const float* __restrict__ X,
                            float* __restrict__ out,
                            float* __restrict__ xlast) {
  __shared__ float tile[64][129];
  int t = blockIdx.x >> 2;
  int k0 = (blockIdx.x & 3) * 128;
  const float* src = X + (size_t)t * (BB * IN_) + k0;
#pragma unroll
  for (int j = 0; j < 8; ++j) {
    int f = threadIdx.x + j * 256;   // float4 index in 64x128 tile
    int b = f >> 5;
    int m = (f & 31) * 4;
    float4 v = *reinterpret_cast<const float4*>(src + b * IN_ + m);
    tile[b][m + 0] = v.x; tile[b][m + 1] = v.y;
    tile[b][m + 2] = v.z; tile[b][m + 3] = v.w;
  }
  __syncthreads();
  float* dst = (t < TT - 1) ? (out + (size_t)(t + 1) * SLICE) : xlast;
  int b = threadIdx.x & 63;
  int ks = threadIdx.x >> 6;
#pragma unroll
  for (int u = 0; u < 32; ++u) {
    int kk = ks * 32 + u;
    dst[(k0 + kk) * BB + b] = tile[b][kk];
  }
}

// Persistent LSTM: 256 blocks x 512 threads, 1 block/CU.
// Thread mapping: tid = ks*8 + bt, ks in [0,64) = 16-k slice, bt in [0,8) = 8-b tile.
// Round-5 change vs verified round-2:
//  * H loads: asm global_load_dwordx4 sc0 sc1 (32 loads, was 64) with
//    counted s_waitcnt vmcnt(6/4/2/0) + sched_barrier(0) after each wait
//    (rule #18) — depth-3 lookahead, 8 loads in flight, order pinned.
//  * H-state writes: atomic exchange (LLC-completion-ack'd before barrier).
//  * X path / reduction / gate phase: byte-identical to round 2 (verified).
__global__ void __launch_bounds__(512, 2) lstm_rec(
    const float* __restrict__ W4, const float* __restrict__ bias,
    const float* __restrict__ h0p, const float* __restrict__ c0p,
    float* __restrict__ Hb0, float* __restrict__ Hb1,
    const float* __restrict__ xlast, float* __restrict__ out,
    unsigned* __restrict__ ctr) {
  __shared__ float wlds[KTOT * 8];      // 32 KB, XOR-swizzled float4 slots
  __shared__ float red3[8 * 8 * 72];    // [wave][hg][bt*9 + i], 18 KB, 9-pad
  const int tid = threadIdx.x;
  const int blk = blockIdx.x;
  const int wv = __builtin_amdgcn_readfirstlane(tid >> 6);  // wave id 0..7
  const int lane = tid & 63;
  const int ks = tid >> 3;   // k-slice 0..63 (16 k each); waves 0-3 = X, 4-7 = H
  const int bt = tid & 7;    // b-tile (8 consecutive batch elems)
  const int h0c = blk * 2;
  unsigned bar_target = 256;

  // One-time weight stage into LDS (XOR-swizzled, bijective:
  // f4' = (k*2+r) ^ (((k>>4)&3)<<1 | ((k>>6)&1)); source bits k4..k6 are
  // disjoint from target bits 0..2).
  {
    const float4* Wsrc = reinterpret_cast<const float4*>(W4);
    float4* Wdst = reinterpret_cast<float4*>(wlds);
    for (int i = tid; i < KTOT * 2; i += 512) {
      int k = i >> 1, r = i & 1;
      int swz = (((k >> 4) & 3) << 1) | ((k >> 6) & 1);
      Wdst[((k * 2) + r) ^ swz] = Wsrc[(k << 9) + h0c + r];
    }
  }

  // Init: H_{-1} = h0 into Hb0 in [h][b] layout (LLC-ack'd); C from c0.
  float C = 0.0f;
  float bias_r[4] = {0.f, 0.f, 0.f, 0.f};
  if (tid < 128) {
    int hh = h0c + (tid >> 6);
    int b = tid & 63;
    st_llc_ack(&Hb0[hh * BB + b], h0p[b * HID_ + hh]);
    C = c0p[b * HID_ + hh];
#pragma unroll
    for (int g = 0; g < 4; ++g) bias_r[g] = bias[g * HID_ + hh];
  }
  gridbar(ctr, bar_target); bar_target += 256;

  // Thread-invariant swizzled W base (ks*32 is 32-aligned; swz<8 stays in-tile).
  const int swz = ((ks & 3) << 1) | ((ks >> 2) & 1);
  const float4* wbase = reinterpret_cast<const float4*>(wlds) + ks * 32;

  for (int t = 0; t < TT; ++t) {
    const float* Hprev = (t & 1) ? Hb1 : Hb0;
    float* Hnext = (t & 1) ? Hb0 : Hb1;
    const float* Xs = (t < TT - 1) ? (out + (size_t)(t + 1) * SLICE) : xlast;

    // acc[h][g][bpair] : 32 v2f = 64 floats, fully static-indexed.
    v2f acc[2][4][4];
#pragma unroll
    for (int h = 0; h < 2; ++h)
#pragma unroll
      for (int g = 0; g < 4; ++g)
#pragma unroll
        for (int p = 0; p < 4; ++p) acc[h][g][p] = (v2f){0.f, 0.f};

    if (wv < 4) {
      // X half: k = ks*16 + j, normal L2-cached loads, 8 b per thread.
      // UNCHANGED from verified round 2 (X data is static; safe under
      // any reordering; compiler scheduling passed twice).
      const float4* Ax = reinterpret_cast<const float4*>(Xs) + ks * 256 + bt * 2;
#pragma unroll 4
      for (int j = 0; j < 16; ++j) {
        float4 a0 = Ax[j * 16];
        float4 a1 = Ax[j * 16 + 1];
        float4 wa = wbase[(j * 2) ^ swz];
        float4 wb = wbase[(j * 2 + 1) ^ swz];
        v2f av[4] = {{a0.x, a0.y}, {a0.z, a0.w}, {a1.x, a1.y}, {a1.z, a1.w}};
        const float wg[2][4] = {{wa.x, wa.y, wa.z, wa.w},
                                {wb.x, wb.y, wb.z, wb.w}};
#pragma unroll
        for (int h = 0; h < 2; ++h)
#pragma unroll
          for (int g = 0; g < 4; ++g) {
            v2f wvv = {wg[h][g], wg[h][g]};
#pragma unroll
            for (int p = 0; p < 4; ++p)
              acc[h][g][p] = __builtin_elementwise_fma(wvv, av[p], acc[h][g][p]);
          }
      }
    } else {
      // H half: hand-pipelined LLC loads, depth-3 lookahead, counted vmcnt.
      // Per-wave vmcnt counts ONLY these asm loads (H waves issue no other
      // vmem inside the loop), so the counted waits are exact.
      const v4f* Ahf4 = reinterpret_cast<const v4f*>(Hprev) +
                        (ks * 16 - IN_) * 16 + bt * 2;
      v4f hw[4][2];  // rotating 4-group window, static-indexed under unroll
      // Prologue: groups 0..2 (6 loads in flight).
#pragma unroll
      for (int j = 0; j < 3; ++j) {
        hw[j][0] = ld_llc128_async(Ahf4 + j * 16);
        hw[j][1] = ld_llc128_async(Ahf4 + j * 16 + 1);
      }
#pragma unroll
      for (int j = 0; j < 16; ++j) {
        if (j + 3 < 16) {  // folds at compile time under full unroll
          hw[(j + 3) & 3][0] = ld_llc128_async(Ahf4 + (j + 3) * 16);
          hw[(j + 3) & 3][1] = ld_llc128_async(Ahf4 + (j + 3) * 16 + 1);
        }
        // Wait until group j's 2 loads completed (newest groups may remain).
        if (j <= 12)      asm volatile("s_waitcnt vmcnt(6)" ::: "memory");
        else if (j == 13) asm volatile("s_waitcnt vmcnt(4)" ::: "memory");
        else if (j == 14) asm volatile("s_waitcnt vmcnt(2)" ::: "memory");
        else              asm volatile("s_waitcnt vmcnt(0)" ::: "memory");
        __builtin_amdgcn_sched_barrier(0);  // rule #18: pin FMAs below wait
        v4f A = hw[j & 3][0];
        v4f B = hw[j & 3][1];
        float4 wa = wbase[(j * 2) ^ swz];
        float4 wb = wbase[(j * 2 + 1) ^ swz];
        v2f av[4] = {{A.x, A.y}, {A.z, A.w}, {B.x, B.y}, {B.z, B.w}};
        const float wg[2][4] = {{wa.x, wa.y, wa.z, wa.w},
                                {wb.x, wb.y, wb.z, wb.w}};
#pragma unroll
        for (int h = 0; h < 2; ++h)
#pragma unroll
          for (int g = 0; g < 4; ++g) {
            v2f wvv = {wg[h][g], wg[h][g]};
#pragma unroll
            for (int p = 0; p < 4; ++p)
              acc[h][g][p] = __builtin_elementwise_fma(wvv, av[p], acc[h][g][p]);
          }
      }
    }

    // ---- Reduce over the 8 k-slices inside this wave (lane bits 3..5). ----
    // vals idx = hg*8 + i, hg = h*4+g, i = b-within-tile. After 3 stages the
    // lane with (lane>>3)&7 == hg holds vals[i] = sum over its wave's 8 ks.
    float vals[64];
#pragma unroll
    for (int h = 0; h < 2; ++h)
#pragma unroll
      for (int g = 0; g < 4; ++g)
#pragma unroll
        for (int p = 0; p < 4; ++p) {
          vals[(h * 4 + g) * 8 + p * 2]     = acc[h][g][p].x;
          vals[(h * 4 + g) * 8 + p * 2 + 1] = acc[h][g][p].y;
        }
#pragma unroll
    for (int r = 0; r < 32; ++r) vals[r] = plswap32_sum(vals[r], vals[r + 32]);
#pragma unroll
    for (int r = 0; r < 16; ++r) vals[r] = plswap16_sum(vals[r], vals[r + 16]);
    {
      const bool hi = (lane & 8) != 0;
#pragma unroll
      for (int r = 0; r < 8; ++r) {
        float keep = hi ? vals[r + 8] : vals[r];
        float send = hi ? vals[r] : vals[r + 8];
        vals[r] = keep + __shfl_xor(send, 8, 64);
      }
    }
    // Cross-wave combine via LDS: 32 B per thread.
    {
      int hgo = (lane >> 3) & 7;
      float* rp = &red3[(wv * 8 + hgo) * 72 + bt * 9];
#pragma unroll
      for (int i = 0; i < 8; ++i) rp[i] = vals[i];
    }
    __syncthreads();

    if (tid < 128) {
      int hsub = tid >> 6;
      int hh = h0c + hsub;
      int b = tid & 63;
      int boff = (b >> 3) * 9 + (b & 7);
      float gs[4];
#pragma unroll
      for (int g = 0; g < 4; ++g) {
        float s = bias_r[g];
#pragma unroll
        for (int w = 0; w < 8; ++w) s += red3[(w * 8 + hsub * 4 + g) * 72 + boff];
        gs[g] = s;
      }
      float I = sigmoid_fast(gs[0]);
      float F = sigmoid_fast(gs[1]);
      float O = sigmoid_fast(gs[2]);
      float Ctl = tanh_fast(gs[3]);
      C = F * C + I * Ctl;
      float H = O * tanh_fast(C);
      out[(size_t)t * SLICE + b * HID_ + hh] = H;  // final output (normal store)
      st_llc_ack(&Hnext[hh * BB + b], H);          // LLC-ack'd H for next step
    }
    gridbar(ctr, bar_target); bar_target += 256;  // also guards red3 reuse
  }
}

extern "C" void kernel_launch(void* const* d_in, const int* in_sizes, int n_in,
                              void* d_out, int out_size, void* d_ws, size_t ws_size,
                              hipStream_t stream) {
  (void)in_sizes; (void)n_in; (void)out_size; (void)ws_size;
  const float* X    = (const float*)d_in[0];
  const float* Wx   = (const float*)d_in[1];
  const float* Wh   = (const float*)d_in[2];
  const float* bias = (const float*)d_in[3];
  const float* thr  = (const float*)d_in[4];
  const float* h0p  = (const float*)d_in[5];
  const float* c0p  = (const float*)d_in[6];
  float* out = (float*)d_out;

  // ws layout (floats): W4 [1024][512][4] | Hb0 | Hb1 | xlast | ctr (~8.8 MB)
  float* W4 = (float*)d_ws;
  float* Hb0 = W4 + (size_t)KTOT * HID_ * 4;
  float* Hb1 = Hb0 + SLICE;
  float* xlast = Hb1 + SLICE;
  unsigned* ctr = (unsigned*)(xlast + SLICE);

  prep_weights<<<(KTOT * HID_) / 256, 256, 0, stream>>>(Wx, Wh, thr, W4, ctr);
  transpose_x<<<TT * 4, 256, 0, stream>>>(X, out, xlast);

  void* args[] = {&W4, &bias, &h0p, &c0p, &Hb0, &Hb1, &xlast, &out, &ctr};
  hipLaunchCooperativeKernel(reinterpret_cast<void*>(lstm_rec),
                             dim3(256), dim3(512), args, 0, stream);
}